// Round 6
// baseline (529.028 us; speedup 1.0000x reference)
//
#include <hip/hip_runtime.h>

#define NN 100000
#define NE 1600000

#define SCAN_ELEMS 1024
#define SCAN_NB ((NN + SCAN_ELEMS - 1) / SCAN_ELEMS)   // 98

#define NWIN 8
#define WIN_SZ (NN / NWIN)   // 12500
#define NBIN_BLK ((NE + 1023) / 1024)  // 1563

typedef unsigned long long u64;

// ---------------- CSR build ----------------

__global__ __launch_bounds__(256) void hist_kernel(const int* __restrict__ dst,
                                                   int* __restrict__ deg) {
    int e4 = (blockIdx.x * 256 + threadIdx.x) * 4;
    if (e4 >= NE) return;
    int4 d = *reinterpret_cast<const int4*>(dst + e4);
    atomicAdd(&deg[d.x], 1);
    atomicAdd(&deg[d.y], 1);
    atomicAdd(&deg[d.z], 1);
    atomicAdd(&deg[d.w], 1);
}

__global__ __launch_bounds__(256) void scan_pass1(const int* __restrict__ deg,
                                                  int* __restrict__ bsum) {
    int t = threadIdx.x;
    int i4 = blockIdx.x * SCAN_ELEMS + t * 4;
    int s = 0;
    if (i4 < NN) {
        int4 v = *reinterpret_cast<const int4*>(deg + i4);
        s = v.x + v.y + v.z + v.w;
    }
    __shared__ int red[256];
    red[t] = s;
    __syncthreads();
    for (int off = 128; off > 0; off >>= 1) {
        if (t < off) red[t] += red[t + off];
        __syncthreads();
    }
    if (t == 0) bsum[blockIdx.x] = red[0];
}

__global__ __launch_bounds__(128) void scan_pass2(int* __restrict__ bsum,
                                                  int* __restrict__ offsets) {
    int t = threadIdx.x;
    int v = (t < SCAN_NB) ? bsum[t] : 0;
    __shared__ int tmp[128];
    tmp[t] = v;
    __syncthreads();
    for (int off = 1; off < 128; off <<= 1) {
        int u = (t >= off) ? tmp[t - off] : 0;
        __syncthreads();
        tmp[t] += u;
        __syncthreads();
    }
    if (t < SCAN_NB) bsum[t] = tmp[t] - v;
    if (t == SCAN_NB - 1) offsets[NN] = tmp[t];
}

__global__ __launch_bounds__(256) void scan_pass3(const int* __restrict__ deg,
                                                  const int* __restrict__ bsum,
                                                  int* __restrict__ offsets,
                                                  int* __restrict__ cursor) {
    int t = threadIdx.x;
    int i4 = blockIdx.x * SCAN_ELEMS + t * 4;
    int4 v = make_int4(0, 0, 0, 0);
    if (i4 < NN) v = *reinterpret_cast<const int4*>(deg + i4);
    int s = v.x + v.y + v.z + v.w;
    __shared__ int tmp[256];
    tmp[t] = s;
    __syncthreads();
    for (int off = 1; off < 256; off <<= 1) {
        int u = (t >= off) ? tmp[t - off] : 0;
        __syncthreads();
        tmp[t] += u;
        __syncthreads();
    }
    if (i4 < NN) {
        int base = bsum[blockIdx.x] + tmp[t] - s;
        int4 o;
        o.x = base;
        o.y = o.x + v.x;
        o.z = o.y + v.y;
        o.w = o.z + v.z;
        *reinterpret_cast<int4*>(offsets + i4) = o;
        *reinterpret_cast<int4*>(cursor + i4) = o;
    }
}

__global__ __launch_bounds__(64) void init_kernel(const int* __restrict__ offsets,
                                                  int* __restrict__ wcur,
                                                  int* __restrict__ claim) {
    int t = threadIdx.x;
    if (t < NWIN) {
        int v = offsets[t * WIN_SZ];
        wcur[t]  = v;   // bin write cursor (absolute index into rec[])
        claim[t] = v;   // scatterB work-queue cursor (absolute)
    }
}

// Phase A: bin edges by dst-window into packed 8B records, coalesced writes.
// record: hi32 = src(17b) | local_dst(14b)<<17 ; lo32 = weight bits
__global__ __launch_bounds__(256) void bin_kernel(const int* __restrict__ src,
                                                  const int* __restrict__ dst,
                                                  const float* __restrict__ w,
                                                  int* __restrict__ wcur,
                                                  u64* __restrict__ rec) {
    __shared__ int cnt[NWIN], base_l[NWIN], gbase[NWIN], lofs[NWIN], stot;
    __shared__ u64 stage[1024];
    int t = threadIdx.x;
    if (t < NWIN) { cnt[t] = 0; lofs[t] = 0; }
    __syncthreads();

    int e4 = blockIdx.x * 1024 + t * 4;
    bool valid = e4 < NE;   // NE % 4 == 0 -> whole int4 valid or none
    int4 d4 = make_int4(0, 0, 0, 0), s4 = make_int4(0, 0, 0, 0);
    float4 w4 = make_float4(0.f, 0.f, 0.f, 0.f);
    if (valid) {
        d4 = *reinterpret_cast<const int4*>(dst + e4);
        s4 = *reinterpret_cast<const int4*>(src + e4);
        w4 = *reinterpret_cast<const float4*>(w + e4);
    }
    int   da[4] = {d4.x, d4.y, d4.z, d4.w};
    int   sa[4] = {s4.x, s4.y, s4.z, s4.w};
    float wa[4] = {w4.x, w4.y, w4.z, w4.w};
    int wi[4];
    if (valid) {
#pragma unroll
        for (int i = 0; i < 4; ++i) {
            wi[i] = da[i] / WIN_SZ;
            atomicAdd(&cnt[wi[i]], 1);
        }
    }
    __syncthreads();
    if (t < NWIN) {
        int b = 0;
        for (int k = 0; k < t; ++k) b += cnt[k];
        base_l[t] = b;
        gbase[t]  = atomicAdd(&wcur[t], cnt[t]);
        if (t == NWIN - 1) stot = b + cnt[t];
    }
    __syncthreads();
    if (valid) {
#pragma unroll
        for (int i = 0; i < 4; ++i) {
            int p = base_l[wi[i]] + atomicAdd(&lofs[wi[i]], 1);
            u64 hi = (u64)(unsigned)(sa[i] | ((da[i] - wi[i] * WIN_SZ) << 17));
            stage[p] = (hi << 32) | (u64)(unsigned)__float_as_int(wa[i]);
        }
    }
    __syncthreads();
    int tot = stot;
    for (int i = t; i < tot; i += 256) {
        int wsel = 0;
#pragma unroll
        for (int k = 1; k < NWIN; ++k) wsel += (i >= base_l[k]);
        rec[gbase[wsel] + (i - base_l[wsel])] = stage[i];   // coalesced per-window runs
    }
}

// Phase B: each block scatters records of ITS OWN XCD's window (true L2
// pinning via HW_REG_XCC_ID); work-stealing over other windows guarantees
// correctness under any block->XCD mapping.
__device__ __forceinline__ int xcc_id() {
    int x;
    asm("s_getreg_b32 %0, hwreg(HW_REG_XCC_ID, 0, 32)" : "=s"(x));
    return x & (NWIN - 1);
}

__global__ __launch_bounds__(256) void scatterB_kernel(const u64* __restrict__ rec,
                                                       const int* __restrict__ offsets,
                                                       int* __restrict__ cursor,
                                                       int* __restrict__ claim,
                                                       int2* __restrict__ csr) {
    __shared__ int sbase;
    int w0 = xcc_id();
    int t = threadIdx.x;
    for (int k = 0; k < NWIN; ++k) {
        int ww  = (w0 + k) & (NWIN - 1);
        int end = offsets[(ww + 1) * WIN_SZ];
        int wlo = ww * WIN_SZ;
        while (true) {
            if (t == 0) sbase = atomicAdd(&claim[ww], 1024);
            __syncthreads();
            int b = sbase;
            __syncthreads();          // all reads done before t0's next write
            if (b >= end) break;      // uniform
            int n = min(1024, end - b);
            for (int i = t; i < n; i += 256) {
                u64 r = rec[b + i];
                unsigned hi = (unsigned)(r >> 32);
                int s    = (int)(hi & 0x1FFFF);
                int dstn = wlo + (int)(hi >> 17);
                int slot = atomicAdd(&cursor[dstn], 1);
                csr[slot] = make_int2(s, (int)(unsigned)r);
            }
        }
    }
}

// ---------------- dense GEMM: S[N,64] = X[N,K] @ W[K,64] ----------------
// 8 rows per wave; W LDS reads amortized 8x; uniform x addr -> s_load.

template <int K>
__global__ __launch_bounds__(256) void gemm_kernel(const float* __restrict__ X,
                                                   const float* __restrict__ W,
                                                   float* __restrict__ S) {
    __shared__ float Wt[64][K + 1];
    for (int idx = threadIdx.x; idx < K * 64; idx += 256) {
        int k = idx >> 6, j = idx & 63;
        Wt[j][k] = W[idx];
    }
    __syncthreads();

    int wave = threadIdx.x >> 6;
    int lane = threadIdx.x & 63;
    int row0 = (blockIdx.x * 4 + wave) * 8;
    row0 = __builtin_amdgcn_readfirstlane(row0);

    const float* x0 = X + (size_t)row0 * K;
    float acc[8] = {0.f, 0.f, 0.f, 0.f, 0.f, 0.f, 0.f, 0.f};

#pragma unroll 4
    for (int k = 0; k < K; k += 4) {
        float w0 = Wt[lane][k];
        float w1 = Wt[lane][k + 1];
        float w2 = Wt[lane][k + 2];
        float w3 = Wt[lane][k + 3];
#pragma unroll
        for (int r = 0; r < 8; ++r) {
            float4 xv = *reinterpret_cast<const float4*>(x0 + r * K + k);
            acc[r] += xv.x * w0 + xv.y * w1 + xv.z * w2 + xv.w * w3;
        }
    }
#pragma unroll
    for (int r = 0; r < 8; ++r) {
        S[(size_t)(row0 + r) * 64 + lane] = acc[r];
    }
}

// ---------------- SPMM gather ----------------

template <bool RELU>
__global__ __launch_bounds__(256) void spmm_kernel(const int2* __restrict__ csr,
                                                   const int* __restrict__ offsets,
                                                   const float* __restrict__ S,
                                                   const float* __restrict__ bias,
                                                   float* __restrict__ out, int N) {
    int wave = threadIdx.x >> 6;
    int lane = threadIdx.x & 63;
    int row  = blockIdx.x * 4 + wave;
    if (row >= N) return;

    int beg = offsets[row];
    int end = offsets[row + 1];
    float acc = 0.f;
    int e = beg;
    for (; e + 4 <= end; e += 4) {
        int2 e0 = csr[e],     e1 = csr[e + 1];
        int2 e2 = csr[e + 2], e3 = csr[e + 3];
        float v0 = S[e0.x * 64 + lane];
        float v1 = S[e1.x * 64 + lane];
        float v2 = S[e2.x * 64 + lane];
        float v3 = S[e3.x * 64 + lane];
        acc += __int_as_float(e0.y) * v0;
        acc += __int_as_float(e1.y) * v1;
        acc += __int_as_float(e2.y) * v2;
        acc += __int_as_float(e3.y) * v3;
    }
    for (; e < end; ++e) {
        int2 ee = csr[e];
        acc += __int_as_float(ee.y) * S[ee.x * 64 + lane];
    }
    float v = acc + bias[lane];
    if (RELU) v = fmaxf(v, 0.f);
    out[(size_t)row * 64 + lane] = v;
}

// ---------------- launch ----------------

extern "C" void kernel_launch(void* const* d_in, const int* in_sizes, int n_in,
                              void* d_out, int out_size, void* d_ws, size_t ws_size,
                              hipStream_t stream) {
    const float* features = (const float*)d_in[0];
    const int*   src      = (const int*)d_in[1];
    const int*   dst      = (const int*)d_in[2];
    const float* ew       = (const float*)d_in[3];
    const float* W1       = (const float*)d_in[4];
    const float* b1       = (const float*)d_in[5];
    const float* W2       = (const float*)d_in[6];
    const float* b2       = (const float*)d_in[7];
    const float* W3       = (const float*)d_in[8];
    const float* b3       = (const float*)d_in[9];
    float*       out      = (float*)d_out;

    float* s_buf   = (float*)d_ws;                     // NN*64 f32
    float* h_buf   = s_buf + (size_t)NN * 64;          // NN*64 f32 (rec aliases here during build)
    int*   deg     = (int*)(h_buf + (size_t)NN * 64);  // NN
    int*   offsets = deg + NN;                         // NN+4
    int*   cursor  = offsets + NN + 4;                 // NN
    int*   bsum    = cursor + NN;                      // 128
    int*   wcur    = bsum + 128;                       // 8
    int*   claim   = wcur + 8;                         // 8
    int2*  csr     = (int2*)(claim + 8);               // NE packed records
    u64*   rec     = (u64*)h_buf;                      // NE binned records (dead before spmm1)

    (void)hipMemsetAsync(deg, 0, NN * sizeof(int), stream);
    hist_kernel<<<(NE / 4 + 255) / 256, 256, 0, stream>>>(dst, deg);
    scan_pass1<<<SCAN_NB, 256, 0, stream>>>(deg, bsum);
    scan_pass2<<<1, 128, 0, stream>>>(bsum, offsets);
    scan_pass3<<<SCAN_NB, 256, 0, stream>>>(deg, bsum, offsets, cursor);
    init_kernel<<<1, 64, 0, stream>>>(offsets, wcur, claim);
    bin_kernel<<<NBIN_BLK, 256, 0, stream>>>(src, dst, ew, wcur, rec);
    scatterB_kernel<<<1024, 256, 0, stream>>>(rec, offsets, cursor, claim, csr);

    int grid_gemm = NN / 32;
    int grid_rows = (NN + 3) / 4;
    gemm_kernel<128><<<grid_gemm, 256, 0, stream>>>(features, W1, s_buf);
    spmm_kernel<true><<<grid_rows, 256, 0, stream>>>(csr, offsets, s_buf, b1, h_buf, NN);
    gemm_kernel<64><<<grid_gemm, 256, 0, stream>>>(h_buf, W2, s_buf);
    spmm_kernel<true><<<grid_rows, 256, 0, stream>>>(csr, offsets, s_buf, b2, h_buf, NN);
    gemm_kernel<64><<<grid_gemm, 256, 0, stream>>>(h_buf, W3, s_buf);
    spmm_kernel<false><<<grid_rows, 256, 0, stream>>>(csr, offsets, s_buf, b3, out, NN);
}

// Round 8
// 422.847 us; speedup vs baseline: 1.2511x; 1.2511x over previous
//
#include <hip/hip_runtime.h>

#define NN 100000
#define NE 1600000

#define SCAN_ELEMS 1024
#define SCAN_NB ((NN + SCAN_ELEMS - 1) / SCAN_ELEMS)   // 98

#define BNODES 256                       // nodes per sort bucket
#define NBUCK ((NN + BNODES - 1) / BNODES)  // 391
#define TILE 4096                        // edges per bin tile
#define NTILE ((NE + TILE - 1) / TILE)   // 391
#define CAP 5120                         // LDS sort capacity (mean 4096, ~16 sigma)

typedef unsigned long long u64;

// ---------------- node-degree histogram + scan -> offsets ----------------

__global__ __launch_bounds__(256) void hist_kernel(const int* __restrict__ dst,
                                                   int* __restrict__ deg) {
    int e4 = (blockIdx.x * 256 + threadIdx.x) * 4;
    if (e4 >= NE) return;
    int4 d = *reinterpret_cast<const int4*>(dst + e4);
    atomicAdd(&deg[d.x], 1);
    atomicAdd(&deg[d.y], 1);
    atomicAdd(&deg[d.z], 1);
    atomicAdd(&deg[d.w], 1);
}

__global__ __launch_bounds__(256) void scan_pass1(const int* __restrict__ deg,
                                                  int* __restrict__ bsum) {
    int t = threadIdx.x;
    int i4 = blockIdx.x * SCAN_ELEMS + t * 4;
    int s = 0;
    if (i4 < NN) {
        int4 v = *reinterpret_cast<const int4*>(deg + i4);
        s = v.x + v.y + v.z + v.w;
    }
    __shared__ int red[256];
    red[t] = s;
    __syncthreads();
    for (int off = 128; off > 0; off >>= 1) {
        if (t < off) red[t] += red[t + off];
        __syncthreads();
    }
    if (t == 0) bsum[blockIdx.x] = red[0];
}

__global__ __launch_bounds__(128) void scan_pass2(int* __restrict__ bsum,
                                                  int* __restrict__ offsets) {
    int t = threadIdx.x;
    int v = (t < SCAN_NB) ? bsum[t] : 0;
    __shared__ int tmp[128];
    tmp[t] = v;
    __syncthreads();
    for (int off = 1; off < 128; off <<= 1) {
        int u = (t >= off) ? tmp[t - off] : 0;
        __syncthreads();
        tmp[t] += u;
        __syncthreads();
    }
    if (t < SCAN_NB) bsum[t] = tmp[t] - v;
    if (t == SCAN_NB - 1) offsets[NN] = tmp[t];
}

__global__ __launch_bounds__(256) void scan_pass3(const int* __restrict__ deg,
                                                  const int* __restrict__ bsum,
                                                  int* __restrict__ offsets) {
    int t = threadIdx.x;
    int i4 = blockIdx.x * SCAN_ELEMS + t * 4;
    int4 v = make_int4(0, 0, 0, 0);
    if (i4 < NN) v = *reinterpret_cast<const int4*>(deg + i4);
    int s = v.x + v.y + v.z + v.w;
    __shared__ int tmp[256];
    tmp[t] = s;
    __syncthreads();
    for (int off = 1; off < 256; off <<= 1) {
        int u = (t >= off) ? tmp[t - off] : 0;
        __syncthreads();
        tmp[t] += u;
        __syncthreads();
    }
    if (i4 < NN) {
        int base = bsum[blockIdx.x] + tmp[t] - s;
        int4 o;
        o.x = base;
        o.y = o.x + v.x;
        o.z = o.y + v.y;
        o.w = o.z + v.z;
        *reinterpret_cast<int4*>(offsets + i4) = o;
    }
}

__global__ __launch_bounds__(512) void initw_kernel(const int* __restrict__ offsets,
                                                    int* __restrict__ wcur) {
    int t = threadIdx.x;
    if (t < NBUCK) wcur[t] = offsets[t << 8];   // bucket base in rec[]/csr[]
}

// ---------------- phase A: bin edges into 391 buckets, coalesced writes ----
// record: hi32 = src(17b) | local_dst(8b)<<17 ; lo32 = weight bits.
// Tile reordered in LDS so global writes are contiguous per-bucket runs.
// NOTE: NBUCK(391) > blockDim(256) -> ALL per-bucket loops must stride!

__global__ __launch_bounds__(256) void bin_kernel(const int* __restrict__ src,
                                                  const int* __restrict__ dst,
                                                  const float* __restrict__ w,
                                                  int* __restrict__ wcur,
                                                  u64* __restrict__ rec) {
    __shared__ int cnt[512];          // padded to 512, zeroed
    __shared__ int base_l[512];
    __shared__ int gbase[NBUCK];
    __shared__ int lofs[NBUCK];
    __shared__ int scan2[256];
    __shared__ u64 stage[TILE];
    __shared__ unsigned short stage_b[TILE];

    int t = threadIdx.x;
    cnt[t] = 0;
    cnt[t + 256] = 0;
    for (int b = t; b < NBUCK; b += 256) lofs[b] = 0;   // strided: NBUCK > 256
    __syncthreads();

    int e0 = blockIdx.x * TILE + t * 16;
    bool valid = e0 < NE;   // tile tails are multiples of 16 -> all-or-nothing
    int d[16], s[16];
    float ww[16];
    if (valid) {
#pragma unroll
        for (int q = 0; q < 4; ++q) {
            int4 dv = *reinterpret_cast<const int4*>(dst + e0 + q * 4);
            int4 sv = *reinterpret_cast<const int4*>(src + e0 + q * 4);
            float4 wv = *reinterpret_cast<const float4*>(w + e0 + q * 4);
            d[q * 4 + 0] = dv.x; d[q * 4 + 1] = dv.y; d[q * 4 + 2] = dv.z; d[q * 4 + 3] = dv.w;
            s[q * 4 + 0] = sv.x; s[q * 4 + 1] = sv.y; s[q * 4 + 2] = sv.z; s[q * 4 + 3] = sv.w;
            ww[q * 4 + 0] = wv.x; ww[q * 4 + 1] = wv.y; ww[q * 4 + 2] = wv.z; ww[q * 4 + 3] = wv.w;
        }
#pragma unroll
        for (int i = 0; i < 16; ++i) atomicAdd(&cnt[d[i] >> 8], 1);
    }
    __syncthreads();

    // exclusive scan of cnt[0..511] with 256 threads (pairwise + Hillis-Steele)
    int pair = cnt[2 * t] + cnt[2 * t + 1];
    scan2[t] = pair;
    __syncthreads();
    for (int off = 1; off < 256; off <<= 1) {
        int u = (t >= off) ? scan2[t - off] : 0;
        __syncthreads();
        scan2[t] += u;
        __syncthreads();
    }
    int excl = scan2[t] - pair;
    base_l[2 * t]     = excl;
    base_l[2 * t + 1] = excl + cnt[2 * t];
    for (int b = t; b < NBUCK; b += 256)                 // strided: NBUCK > 256
        gbase[b] = atomicAdd(&wcur[b], cnt[b]);
    __syncthreads();

    if (valid) {
#pragma unroll
        for (int i = 0; i < 16; ++i) {
            int b = d[i] >> 8;
            int p = base_l[b] + atomicAdd(&lofs[b], 1);
            u64 hi = (u64)(unsigned)(s[i] | ((d[i] & 0xFF) << 17));
            stage[p]   = (hi << 32) | (u64)(unsigned)__float_as_int(ww[i]);
            stage_b[p] = (unsigned short)b;
        }
    }
    __syncthreads();

    int tot = scan2[255];
    for (int i = t; i < tot; i += 256) {
        int b = stage_b[i];
        rec[gbase[b] + (i - base_l[b])] = stage[i];   // contiguous per-bucket runs
    }
}

// ---------------- phase B: per-bucket LDS counting sort -> CSR --------------
// Slots come straight from offsets[] (no second histogram). Random 8B writes
// land in LDS (cheap); global write is one coalesced stream per bucket.

__global__ __launch_bounds__(256) void sort_kernel(const u64* __restrict__ rec,
                                                   const int* __restrict__ offsets,
                                                   int2* __restrict__ csr) {
    __shared__ int2 outb[CAP];
    __shared__ int off_l[BNODES];
    __shared__ int ctr[BNODES];

    int b = blockIdx.x;
    int node0 = b << 8;
    int t = threadIdx.x;
    int gbase = offsets[node0];                       // node0 <= 99840 < NN
    int gend  = offsets[min(node0 + BNODES, NN)];
    int cntb  = gend - gbase;

    if (t < BNODES) {
        off_l[t] = offsets[min(node0 + t, NN)] - gbase;
        ctr[t] = 0;
    }
    __syncthreads();

    if (cntb <= CAP) {
        for (int i = t; i < cntb; i += 256) {
            u64 r = rec[gbase + i];
            unsigned hi = (unsigned)(r >> 32);
            int n = (int)(hi >> 17);
            int slot = off_l[n] + atomicAdd(&ctr[n], 1);
            outb[slot] = make_int2((int)(hi & 0x1FFFF), (int)(unsigned)r);
        }
        __syncthreads();
        for (int i = t; i < cntb; i += 256)
            csr[gbase + i] = outb[i];
    } else {
        // overflow fallback (never for this input): direct global scatter
        for (int i = t; i < cntb; i += 256) {
            u64 r = rec[gbase + i];
            unsigned hi = (unsigned)(r >> 32);
            int n = (int)(hi >> 17);
            int slot = off_l[n] + atomicAdd(&ctr[n], 1);
            csr[gbase + slot] = make_int2((int)(hi & 0x1FFFF), (int)(unsigned)r);
        }
    }
}

// ---------------- dense GEMM: S[N,64] = X[N,K] @ W[K,64] ----------------
// 8 rows per wave; W LDS reads amortized 8x; uniform x addr -> s_load.

template <int K>
__global__ __launch_bounds__(256) void gemm_kernel(const float* __restrict__ X,
                                                   const float* __restrict__ W,
                                                   float* __restrict__ S) {
    __shared__ float Wt[64][K + 1];
    for (int idx = threadIdx.x; idx < K * 64; idx += 256) {
        int k = idx >> 6, j = idx & 63;
        Wt[j][k] = W[idx];
    }
    __syncthreads();

    int wave = threadIdx.x >> 6;
    int lane = threadIdx.x & 63;
    int row0 = (blockIdx.x * 4 + wave) * 8;
    row0 = __builtin_amdgcn_readfirstlane(row0);

    const float* x0 = X + (size_t)row0 * K;
    float acc[8] = {0.f, 0.f, 0.f, 0.f, 0.f, 0.f, 0.f, 0.f};

#pragma unroll 4
    for (int k = 0; k < K; k += 4) {
        float w0 = Wt[lane][k];
        float w1 = Wt[lane][k + 1];
        float w2 = Wt[lane][k + 2];
        float w3 = Wt[lane][k + 3];
#pragma unroll
        for (int r = 0; r < 8; ++r) {
            float4 xv = *reinterpret_cast<const float4*>(x0 + r * K + k);
            acc[r] += xv.x * w0 + xv.y * w1 + xv.z * w2 + xv.w * w3;
        }
    }
#pragma unroll
    for (int r = 0; r < 8; ++r) {
        S[(size_t)(row0 + r) * 64 + lane] = acc[r];
    }
}

// ---------------- SPMM gather ----------------

template <bool RELU>
__global__ __launch_bounds__(256) void spmm_kernel(const int2* __restrict__ csr,
                                                   const int* __restrict__ offsets,
                                                   const float* __restrict__ S,
                                                   const float* __restrict__ bias,
                                                   float* __restrict__ out, int N) {
    int wave = threadIdx.x >> 6;
    int lane = threadIdx.x & 63;
    int row  = blockIdx.x * 4 + wave;
    if (row >= N) return;

    int beg = offsets[row];
    int end = offsets[row + 1];
    float acc = 0.f;
    int e = beg;
    for (; e + 4 <= end; e += 4) {
        int2 e0 = csr[e],     e1 = csr[e + 1];
        int2 e2 = csr[e + 2], e3 = csr[e + 3];
        float v0 = S[e0.x * 64 + lane];
        float v1 = S[e1.x * 64 + lane];
        float v2 = S[e2.x * 64 + lane];
        float v3 = S[e3.x * 64 + lane];
        acc += __int_as_float(e0.y) * v0;
        acc += __int_as_float(e1.y) * v1;
        acc += __int_as_float(e2.y) * v2;
        acc += __int_as_float(e3.y) * v3;
    }
    for (; e < end; ++e) {
        int2 ee = csr[e];
        acc += __int_as_float(ee.y) * S[ee.x * 64 + lane];
    }
    float v = acc + bias[lane];
    if (RELU) v = fmaxf(v, 0.f);
    out[(size_t)row * 64 + lane] = v;
}

// ---------------- launch ----------------

extern "C" void kernel_launch(void* const* d_in, const int* in_sizes, int n_in,
                              void* d_out, int out_size, void* d_ws, size_t ws_size,
                              hipStream_t stream) {
    const float* features = (const float*)d_in[0];
    const int*   src      = (const int*)d_in[1];
    const int*   dst      = (const int*)d_in[2];
    const float* ew       = (const float*)d_in[3];
    const float* W1       = (const float*)d_in[4];
    const float* b1       = (const float*)d_in[5];
    const float* W2       = (const float*)d_in[6];
    const float* b2       = (const float*)d_in[7];
    const float* W3       = (const float*)d_in[8];
    const float* b3       = (const float*)d_in[9];
    float*       out      = (float*)d_out;

    float* s_buf   = (float*)d_ws;                     // NN*64 f32
    float* h_buf   = s_buf + (size_t)NN * 64;          // NN*64 f32 (rec aliases; dead before spmm1)
    int*   deg     = (int*)(h_buf + (size_t)NN * 64);  // NN
    int*   offsets = deg + NN;                         // NN+4
    int*   bsum    = offsets + NN + 4;                 // 128
    int*   wcur    = bsum + 128;                       // NBUCK (pad 512)
    int2*  csr     = (int2*)(wcur + 512);              // NE packed records
    u64*   rec     = (u64*)h_buf;                      // NE binned records

    (void)hipMemsetAsync(deg, 0, NN * sizeof(int), stream);
    hist_kernel<<<(NE / 4 + 255) / 256, 256, 0, stream>>>(dst, deg);
    scan_pass1<<<SCAN_NB, 256, 0, stream>>>(deg, bsum);
    scan_pass2<<<1, 128, 0, stream>>>(bsum, offsets);
    scan_pass3<<<SCAN_NB, 256, 0, stream>>>(deg, bsum, offsets);
    initw_kernel<<<1, 512, 0, stream>>>(offsets, wcur);
    bin_kernel<<<NTILE, 256, 0, stream>>>(src, dst, ew, wcur, rec);
    sort_kernel<<<NBUCK, 256, 0, stream>>>(rec, offsets, csr);

    int grid_gemm = NN / 32;
    int grid_rows = (NN + 3) / 4;
    gemm_kernel<128><<<grid_gemm, 256, 0, stream>>>(features, W1, s_buf);
    spmm_kernel<true><<<grid_rows, 256, 0, stream>>>(csr, offsets, s_buf, b1, h_buf, NN);
    gemm_kernel<64><<<grid_gemm, 256, 0, stream>>>(h_buf, W2, s_buf);
    spmm_kernel<true><<<grid_rows, 256, 0, stream>>>(csr, offsets, s_buf, b2, h_buf, NN);
    gemm_kernel<64><<<grid_gemm, 256, 0, stream>>>(h_buf, W3, s_buf);
    spmm_kernel<false><<<grid_rows, 256, 0, stream>>>(csr, offsets, s_buf, b3, out, NN);
}

// Round 9
// 399.412 us; speedup vs baseline: 1.3245x; 1.0587x over previous
//
#include <hip/hip_runtime.h>

#define NN 100000
#define NE 1600000

#define SCAN_ELEMS 1024
#define SCAN_NB ((NN + SCAN_ELEMS - 1) / SCAN_ELEMS)   // 98

#define BNODES 256                       // nodes per sort bucket
#define NBUCK ((NN + BNODES - 1) / BNODES)  // 391
#define TILE 4096                        // edges per bin tile
#define NTILE ((NE + TILE - 1) / TILE)   // 391
#define CAP 5120                         // LDS sort capacity

typedef unsigned long long u64;

// ---------------- node-degree histogram + scan -> offsets ----------------

__global__ __launch_bounds__(256) void hist_kernel(const int* __restrict__ dst,
                                                   int* __restrict__ deg) {
    int e4 = (blockIdx.x * 256 + threadIdx.x) * 4;
    if (e4 >= NE) return;
    int4 d = *reinterpret_cast<const int4*>(dst + e4);
    atomicAdd(&deg[d.x], 1);
    atomicAdd(&deg[d.y], 1);
    atomicAdd(&deg[d.z], 1);
    atomicAdd(&deg[d.w], 1);
}

__global__ __launch_bounds__(256) void scan_pass1(const int* __restrict__ deg,
                                                  int* __restrict__ bsum) {
    int t = threadIdx.x;
    int i4 = blockIdx.x * SCAN_ELEMS + t * 4;
    int s = 0;
    if (i4 < NN) {
        int4 v = *reinterpret_cast<const int4*>(deg + i4);
        s = v.x + v.y + v.z + v.w;
    }
    __shared__ int red[256];
    red[t] = s;
    __syncthreads();
    for (int off = 128; off > 0; off >>= 1) {
        if (t < off) red[t] += red[t + off];
        __syncthreads();
    }
    if (t == 0) bsum[blockIdx.x] = red[0];
}

__global__ __launch_bounds__(128) void scan_pass2(int* __restrict__ bsum,
                                                  int* __restrict__ offsets) {
    int t = threadIdx.x;
    int v = (t < SCAN_NB) ? bsum[t] : 0;
    __shared__ int tmp[128];
    tmp[t] = v;
    __syncthreads();
    for (int off = 1; off < 128; off <<= 1) {
        int u = (t >= off) ? tmp[t - off] : 0;
        __syncthreads();
        tmp[t] += u;
        __syncthreads();
    }
    if (t < SCAN_NB) bsum[t] = tmp[t] - v;
    if (t == SCAN_NB - 1) offsets[NN] = tmp[t];
}

__global__ __launch_bounds__(256) void scan_pass3(const int* __restrict__ deg,
                                                  const int* __restrict__ bsum,
                                                  int* __restrict__ offsets) {
    int t = threadIdx.x;
    int i4 = blockIdx.x * SCAN_ELEMS + t * 4;
    int4 v = make_int4(0, 0, 0, 0);
    if (i4 < NN) v = *reinterpret_cast<const int4*>(deg + i4);
    int s = v.x + v.y + v.z + v.w;
    __shared__ int tmp[256];
    tmp[t] = s;
    __syncthreads();
    for (int off = 1; off < 256; off <<= 1) {
        int u = (t >= off) ? tmp[t - off] : 0;
        __syncthreads();
        tmp[t] += u;
        __syncthreads();
    }
    if (i4 < NN) {
        int base = bsum[blockIdx.x] + tmp[t] - s;
        int4 o;
        o.x = base;
        o.y = o.x + v.x;
        o.z = o.y + v.y;
        o.w = o.z + v.z;
        *reinterpret_cast<int4*>(offsets + i4) = o;
    }
}

__global__ __launch_bounds__(512) void initw_kernel(const int* __restrict__ offsets,
                                                    int* __restrict__ wcur) {
    int t = threadIdx.x;
    if (t < NBUCK) wcur[t] = offsets[t << 8];
}

// ---------------- phase A: bin edges into 391 buckets, coalesced writes ----

__global__ __launch_bounds__(256) void bin_kernel(const int* __restrict__ src,
                                                  const int* __restrict__ dst,
                                                  const float* __restrict__ w,
                                                  int* __restrict__ wcur,
                                                  u64* __restrict__ rec) {
    __shared__ int cnt[512];
    __shared__ int base_l[512];
    __shared__ int gbase[NBUCK];
    __shared__ int lofs[NBUCK];
    __shared__ int scan2[256];
    __shared__ u64 stage[TILE];
    __shared__ unsigned short stage_b[TILE];

    int t = threadIdx.x;
    cnt[t] = 0;
    cnt[t + 256] = 0;
    for (int b = t; b < NBUCK; b += 256) lofs[b] = 0;   // strided: NBUCK > 256
    __syncthreads();

    int e0 = blockIdx.x * TILE + t * 16;
    bool valid = e0 < NE;
    int d[16], s[16];
    float ww[16];
    if (valid) {
#pragma unroll
        for (int q = 0; q < 4; ++q) {
            int4 dv = *reinterpret_cast<const int4*>(dst + e0 + q * 4);
            int4 sv = *reinterpret_cast<const int4*>(src + e0 + q * 4);
            float4 wv = *reinterpret_cast<const float4*>(w + e0 + q * 4);
            d[q * 4 + 0] = dv.x; d[q * 4 + 1] = dv.y; d[q * 4 + 2] = dv.z; d[q * 4 + 3] = dv.w;
            s[q * 4 + 0] = sv.x; s[q * 4 + 1] = sv.y; s[q * 4 + 2] = sv.z; s[q * 4 + 3] = sv.w;
            ww[q * 4 + 0] = wv.x; ww[q * 4 + 1] = wv.y; ww[q * 4 + 2] = wv.z; ww[q * 4 + 3] = wv.w;
        }
#pragma unroll
        for (int i = 0; i < 16; ++i) atomicAdd(&cnt[d[i] >> 8], 1);
    }
    __syncthreads();

    int pair = cnt[2 * t] + cnt[2 * t + 1];
    scan2[t] = pair;
    __syncthreads();
    for (int off = 1; off < 256; off <<= 1) {
        int u = (t >= off) ? scan2[t - off] : 0;
        __syncthreads();
        scan2[t] += u;
        __syncthreads();
    }
    int excl = scan2[t] - pair;
    base_l[2 * t]     = excl;
    base_l[2 * t + 1] = excl + cnt[2 * t];
    for (int b = t; b < NBUCK; b += 256)
        gbase[b] = atomicAdd(&wcur[b], cnt[b]);
    __syncthreads();

    if (valid) {
#pragma unroll
        for (int i = 0; i < 16; ++i) {
            int b = d[i] >> 8;
            int p = base_l[b] + atomicAdd(&lofs[b], 1);
            u64 hi = (u64)(unsigned)(s[i] | ((d[i] & 0xFF) << 17));
            stage[p]   = (hi << 32) | (u64)(unsigned)__float_as_int(ww[i]);
            stage_b[p] = (unsigned short)b;
        }
    }
    __syncthreads();

    int tot = scan2[255];
    for (int i = t; i < tot; i += 256) {
        int b = stage_b[i];
        rec[gbase[b] + (i - base_l[b])] = stage[i];
    }
}

// ---------------- phase B: per-bucket LDS counting sort -> CSR --------------

__global__ __launch_bounds__(256) void sort_kernel(const u64* __restrict__ rec,
                                                   const int* __restrict__ offsets,
                                                   int2* __restrict__ csr) {
    __shared__ int2 outb[CAP];
    __shared__ int off_l[BNODES];
    __shared__ int ctr[BNODES];

    int b = blockIdx.x;
    int node0 = b << 8;
    int t = threadIdx.x;
    int gbase = offsets[node0];
    int gend  = offsets[min(node0 + BNODES, NN)];
    int cntb  = gend - gbase;

    if (t < BNODES) {
        off_l[t] = offsets[min(node0 + t, NN)] - gbase;
        ctr[t] = 0;
    }
    __syncthreads();

    if (cntb <= CAP) {
        for (int i = t; i < cntb; i += 256) {
            u64 r = rec[gbase + i];
            unsigned hi = (unsigned)(r >> 32);
            int n = (int)(hi >> 17);
            int slot = off_l[n] + atomicAdd(&ctr[n], 1);
            outb[slot] = make_int2((int)(hi & 0x1FFFF), (int)(unsigned)r);
        }
        __syncthreads();
        for (int i = t; i < cntb; i += 256)
            csr[gbase + i] = outb[i];
    } else {
        for (int i = t; i < cntb; i += 256) {
            u64 r = rec[gbase + i];
            unsigned hi = (unsigned)(r >> 32);
            int n = (int)(hi >> 17);
            int slot = off_l[n] + atomicAdd(&ctr[n], 1);
            csr[gbase + slot] = make_int2((int)(hi & 0x1FFFF), (int)(unsigned)r);
        }
    }
}

// ---------------- dense GEMM: S[N,64] = X[N,K] @ W[K,64] ----------------
// lane = row (VMEM per-lane x loads, deep queues, lines fully consumed);
// W[k][c] wave-uniform -> s_load dwordx16 on the SCALAR pipe (W is L2/K$-hot,
// tiny). v_fmac acc[c], s_w[c], v_x: 1 SGPR operand per VALU op = legal.
// Wave = 64 rows x 32 cols; acc[32]. Store staged through padded LDS so
// global writes are full-line coalesced (sub-line scatter writeback trap).

#define QUAD(XS, KB)                                                        \
    {                                                                       \
        const float* wr = wbase + (KB) * 64;                                \
        _Pragma("unroll") for (int c = 0; c < 32; ++c)                      \
            acc[c] = fmaf(wr[c], (XS), acc[c]);                             \
    }

template <int K>
__global__ __launch_bounds__(256) void gemm_kernel(const float* __restrict__ X,
                                                   const float* __restrict__ W,
                                                   float* __restrict__ S) {
    __shared__ float tr[4][64][33];   // per-wave transpose buffer (8448 B each)

    int t    = threadIdx.x;
    int wave = t >> 6;
    int lane = t & 63;
    int ch   = __builtin_amdgcn_readfirstlane(wave & 1);   // col half: 0/1
    int rt   = __builtin_amdgcn_readfirstlane(wave >> 1);  // row half: 0/1
    int r0   = blockIdx.x * 128 + rt * 64;
    int row  = r0 + lane;
    int rl   = min(row, NN - 1);

    const float* xrow  = X + (size_t)rl * K;
    const float* wbase = W + ch * 32;

    float acc[32];
#pragma unroll
    for (int c = 0; c < 32; ++c) acc[c] = 0.f;

#pragma unroll
    for (int kk = 0; kk < K; kk += 32) {
        float4 x0 = *reinterpret_cast<const float4*>(xrow + kk);
        float4 x1 = *reinterpret_cast<const float4*>(xrow + kk + 4);
        float4 x2 = *reinterpret_cast<const float4*>(xrow + kk + 8);
        float4 x3 = *reinterpret_cast<const float4*>(xrow + kk + 12);
        float4 x4 = *reinterpret_cast<const float4*>(xrow + kk + 16);
        float4 x5 = *reinterpret_cast<const float4*>(xrow + kk + 20);
        float4 x6 = *reinterpret_cast<const float4*>(xrow + kk + 24);
        float4 x7 = *reinterpret_cast<const float4*>(xrow + kk + 28);
        QUAD(x0.x, kk + 0)  QUAD(x0.y, kk + 1)  QUAD(x0.z, kk + 2)  QUAD(x0.w, kk + 3)
        QUAD(x1.x, kk + 4)  QUAD(x1.y, kk + 5)  QUAD(x1.z, kk + 6)  QUAD(x1.w, kk + 7)
        QUAD(x2.x, kk + 8)  QUAD(x2.y, kk + 9)  QUAD(x2.z, kk + 10) QUAD(x2.w, kk + 11)
        QUAD(x3.x, kk + 12) QUAD(x3.y, kk + 13) QUAD(x3.z, kk + 14) QUAD(x3.w, kk + 15)
        QUAD(x4.x, kk + 16) QUAD(x4.y, kk + 17) QUAD(x4.z, kk + 18) QUAD(x4.w, kk + 19)
        QUAD(x5.x, kk + 20) QUAD(x5.y, kk + 21) QUAD(x5.z, kk + 22) QUAD(x5.w, kk + 23)
        QUAD(x6.x, kk + 24) QUAD(x6.y, kk + 25) QUAD(x6.z, kk + 26) QUAD(x6.w, kk + 27)
        QUAD(x7.x, kk + 28) QUAD(x7.y, kk + 29) QUAD(x7.z, kk + 30) QUAD(x7.w, kk + 31)
    }

    // stage: lane (=row) writes its 32 cols into padded LDS
#pragma unroll
    for (int c = 0; c < 32; ++c) tr[wave][lane][c] = acc[c];

    // coalesced store: 8 float4-segments per row, rows striped across lanes
    for (int i = lane; i < 64 * 8; i += 64) {
        int r = i >> 3, sg = i & 7;
        if (r0 + r < NN) {
            float4 v = make_float4(tr[wave][r][sg * 4 + 0], tr[wave][r][sg * 4 + 1],
                                   tr[wave][r][sg * 4 + 2], tr[wave][r][sg * 4 + 3]);
            *reinterpret_cast<float4*>(S + (size_t)(r0 + r) * 64 + ch * 32 + sg * 4) = v;
        }
    }
}

// ---------------- SPMM gather ----------------

template <bool RELU>
__global__ __launch_bounds__(256) void spmm_kernel(const int2* __restrict__ csr,
                                                   const int* __restrict__ offsets,
                                                   const float* __restrict__ S,
                                                   const float* __restrict__ bias,
                                                   float* __restrict__ out, int N) {
    int wave = threadIdx.x >> 6;
    int lane = threadIdx.x & 63;
    int row  = blockIdx.x * 4 + wave;
    if (row >= N) return;

    int beg = offsets[row];
    int end = offsets[row + 1];
    float acc = 0.f;
    int e = beg;
    for (; e + 4 <= end; e += 4) {
        int2 e0 = csr[e],     e1 = csr[e + 1];
        int2 e2 = csr[e + 2], e3 = csr[e + 3];
        float v0 = S[e0.x * 64 + lane];
        float v1 = S[e1.x * 64 + lane];
        float v2 = S[e2.x * 64 + lane];
        float v3 = S[e3.x * 64 + lane];
        acc += __int_as_float(e0.y) * v0;
        acc += __int_as_float(e1.y) * v1;
        acc += __int_as_float(e2.y) * v2;
        acc += __int_as_float(e3.y) * v3;
    }
    for (; e < end; ++e) {
        int2 ee = csr[e];
        acc += __int_as_float(ee.y) * S[ee.x * 64 + lane];
    }
    float v = acc + bias[lane];
    if (RELU) v = fmaxf(v, 0.f);
    out[(size_t)row * 64 + lane] = v;
}

// ---------------- launch ----------------

extern "C" void kernel_launch(void* const* d_in, const int* in_sizes, int n_in,
                              void* d_out, int out_size, void* d_ws, size_t ws_size,
                              hipStream_t stream) {
    const float* features = (const float*)d_in[0];
    const int*   src      = (const int*)d_in[1];
    const int*   dst      = (const int*)d_in[2];
    const float* ew       = (const float*)d_in[3];
    const float* W1       = (const float*)d_in[4];
    const float* b1       = (const float*)d_in[5];
    const float* W2       = (const float*)d_in[6];
    const float* b2       = (const float*)d_in[7];
    const float* W3       = (const float*)d_in[8];
    const float* b3       = (const float*)d_in[9];
    float*       out      = (float*)d_out;

    float* s_buf   = (float*)d_ws;                     // NN*64 f32
    float* h_buf   = s_buf + (size_t)NN * 64;          // NN*64 f32 (rec aliases)
    int*   deg     = (int*)(h_buf + (size_t)NN * 64);  // NN
    int*   offsets = deg + NN;                         // NN+4
    int*   bsum    = offsets + NN + 4;                 // 128
    int*   wcur    = bsum + 128;                       // NBUCK (pad 512)
    int2*  csr     = (int2*)(wcur + 512);              // NE packed records
    u64*   rec     = (u64*)h_buf;                      // NE binned records

    (void)hipMemsetAsync(deg, 0, NN * sizeof(int), stream);
    hist_kernel<<<(NE / 4 + 255) / 256, 256, 0, stream>>>(dst, deg);
    scan_pass1<<<SCAN_NB, 256, 0, stream>>>(deg, bsum);
    scan_pass2<<<1, 128, 0, stream>>>(bsum, offsets);
    scan_pass3<<<SCAN_NB, 256, 0, stream>>>(deg, bsum, offsets);
    initw_kernel<<<1, 512, 0, stream>>>(offsets, wcur);
    bin_kernel<<<NTILE, 256, 0, stream>>>(src, dst, ew, wcur, rec);
    sort_kernel<<<NBUCK, 256, 0, stream>>>(rec, offsets, csr);

    int grid_gemm = (NN + 127) / 128;   // 782: 128 rows per block (2 row-halves x 2 col-halves)
    int grid_rows = (NN + 3) / 4;
    gemm_kernel<128><<<grid_gemm, 256, 0, stream>>>(features, W1, s_buf);
    spmm_kernel<true><<<grid_rows, 256, 0, stream>>>(csr, offsets, s_buf, b1, h_buf, NN);
    gemm_kernel<64><<<grid_gemm, 256, 0, stream>>>(h_buf, W2, s_buf);
    spmm_kernel<true><<<grid_rows, 256, 0, stream>>>(csr, offsets, s_buf, b2, h_buf, NN);
    gemm_kernel<64><<<grid_gemm, 256, 0, stream>>>(h_buf, W3, s_buf);
    spmm_kernel<false><<<grid_rows, 256, 0, stream>>>(csr, offsets, s_buf, b3, out, NN);
}